// Round 13
// baseline (3597.105 us; speedup 1.0000x reference)
//
#include <hip/hip_runtime.h>
#include <hip/hip_bf16.h>
#include <hip/hip_fp16.h>

#define D 300
#define D2 150          // f16 pairs per row
#define HD 600
#define NLAYERS 5
#define BN_EPS 1e-5f

// GEMM1: K=300->320 (KS1=10), N=600->640. GEMM2: K=600->640 (KS2=20), N=300->384.
#define KS1 10
#define NT1 5
#define KS2 20
#define NT2 3
#define P1 (NT1*KS1*4096)   // 204800 f16 per layer (w1 tiled)
#define P2 (NT2*KS2*4096)   // 245760 f16 per layer (w2 tiled)

#define SCAN_BLK 1024

typedef _Float16 f16x8 __attribute__((ext_vector_type(8)));
typedef __attribute__((ext_vector_type(4))) float f32x4;

// ---------------------------------------------------------------- f16 helpers
__device__ inline ushort f2h(float x) {
    __half h = __float2half(x);
    return *reinterpret_cast<ushort*>(&h);
}
__device__ inline float h2f(ushort u) {
    __half h;
    *reinterpret_cast<ushort*>(&h) = u;
    return __half2float(h);
}
__device__ inline uint pack2h(float lo, float hi) {
    return (uint)f2h(lo) | ((uint)f2h(hi) << 16);
}

// ---------------------------------------------------------------- zero fill
__global__ __launch_bounds__(256) void zero_kernel(uint4* __restrict__ p, long n4)
{
    long i = (long)blockIdx.x * blockDim.x + threadIdx.x;
    long stride = (long)gridDim.x * blockDim.x;
    uint4 z = make_uint4(0u, 0u, 0u, 0u);
    for (; i < n4; i += stride) p[i] = z;
}

// ---------------------------------------------------------------- embed (h f16)
__global__ __launch_bounds__(256) void embed_kernel(
    const int* __restrict__ an, const int* __restrict__ ch,
    const float* __restrict__ e0, const float* __restrict__ e1,
    uint* __restrict__ h_u, int N)
{
    int node = blockIdx.x * 4 + (threadIdx.x >> 6);
    if (node >= N) return;
    int lane = threadIdx.x & 63;
    const float* r0 = e0 + (size_t)an[node] * D;
    const float* r1 = e1 + (size_t)ch[node] * D;
    uint* hr = h_u + (size_t)node * D2;
    for (int d2 = lane; d2 < D2; d2 += 64) {
        float2 a = *(const float2*)(r0 + d2 * 2);
        float2 b = *(const float2*)(r1 + d2 * 2);
        hr[d2] = pack2h(a.x + b.x, a.y + b.y);
    }
}

// ---------------------------------------------------------------- CSR build (once)
__global__ __launch_bounds__(256) void count_kernel(
    const int* __restrict__ dst, int* __restrict__ deg, int E)
{
    int e = blockIdx.x * 256 + threadIdx.x;
    if (e < E) atomicAdd(&deg[dst[e]], 1);
}

__global__ __launch_bounds__(256) void scan_part_kernel(
    const int* __restrict__ deg, int* __restrict__ part, int N)
{
    __shared__ int sm[256];
    int b = blockIdx.x, t = threadIdx.x;
    int base = b * SCAN_BLK + t * 4;
    int s = 0;
#pragma unroll
    for (int j = 0; j < 4; ++j) { int i = base + j; if (i < N) s += deg[i]; }
    sm[t] = s;
    __syncthreads();
    for (int off = 128; off > 0; off >>= 1) {
        if (t < off) sm[t] += sm[t + off];
        __syncthreads();
    }
    if (t == 0) part[b] = sm[0];
}

__global__ __launch_bounds__(256) void scan_top_kernel(int* __restrict__ part, int NB)
{
    __shared__ int sm[256];
    int t = threadIdx.x;
    int own = (t < NB) ? part[t] : 0;
    sm[t] = own;
    __syncthreads();
    for (int off = 1; off < 256; off <<= 1) {
        int u = (t >= off) ? sm[t - off] : 0;
        __syncthreads();
        sm[t] += u;
        __syncthreads();
    }
    if (t < NB) part[t] = sm[t] - own;   // exclusive
}

__global__ __launch_bounds__(256) void scan_write_kernel(
    const int* __restrict__ deg, const int* __restrict__ part,
    int* __restrict__ offsets, int* __restrict__ cursor, int N, int E)
{
    __shared__ int sm[256];
    int b = blockIdx.x, t = threadIdx.x;
    int base = b * SCAN_BLK + t * 4;
    int v[4], s = 0;
#pragma unroll
    for (int j = 0; j < 4; ++j) { int i = base + j; v[j] = (i < N) ? deg[i] : 0; s += v[j]; }
    int own = s;
    sm[t] = s;
    __syncthreads();
    for (int off = 1; off < 256; off <<= 1) {
        int u = (t >= off) ? sm[t - off] : 0;
        __syncthreads();
        sm[t] += u;
        __syncthreads();
    }
    int ex = sm[t] - own + part[b];
#pragma unroll
    for (int j = 0; j < 4; ++j) {
        int i = base + j;
        if (i < N) { offsets[i] = ex; cursor[i] = ex; ex += v[j]; }
    }
    if (b == 0 && t == 0) offsets[N] = E;
}

__global__ __launch_bounds__(256) void scatter_kernel(
    const int* __restrict__ dst, int* __restrict__ cursor,
    int* __restrict__ csr, int E)
{
    int e = blockIdx.x * 256 + threadIdx.x;
    if (e < E) {
        int pos = atomicAdd(&cursor[dst[e]], 1);
        csr[pos] = e;
    }
}

// ---------------------------------------------------------------- edge prep (once): CSR-ordered src + combo id
__global__ __launch_bounds__(256) void eprep_kernel(
    const int* __restrict__ csr, const int* __restrict__ src,
    const int* __restrict__ bt, const int* __restrict__ bd,
    int* __restrict__ esrc, unsigned char* __restrict__ ecomb, int E)
{
    int p = blockIdx.x * 256 + threadIdx.x;
    if (p < E) {
        int e = csr[p];
        esrc[p] = src[e];
        ecomb[p] = (unsigned char)(bt[e] * 3 + bd[e]);
    }
}

// ---------------------------------------------------------------- edge-emb combo table: etab[l][c=bt*3+bd][D2] f16x2
__global__ __launch_bounds__(256) void etab_kernel(
    const float* __restrict__ ee0, const float* __restrict__ ee1,
    uint* __restrict__ etab)
{
    int i = blockIdx.x * 256 + threadIdx.x;
    const int total = NLAYERS * 18 * D2;
    if (i >= total) return;
    int d2 = i % D2;
    int rest = i / D2;
    int c = rest % 18, l = rest / 18;
    int btv = c / 3, bdv = c % 3;
    const float* r0 = ee0 + ((size_t)l * 6 + btv) * D + d2 * 2;
    const float* r1 = ee1 + ((size_t)l * 3 + bdv) * D + d2 * 2;
    etab[i] = pack2h(r0[0] + r1[0], r0[1] + r1[1]);
}

// ---------------------------------------------------------------- BN fold prep
__global__ void prep_bn_kernel(
    const float* __restrict__ b2, const float* __restrict__ gamma,
    const float* __restrict__ beta, const float* __restrict__ mean,
    const float* __restrict__ var, float* __restrict__ scale2,
    float* __restrict__ shift2, int n)
{
    int i = blockIdx.x * blockDim.x + threadIdx.x;
    if (i >= n) return;
    float s = gamma[i] * rsqrtf(var[i] + BN_EPS);
    scale2[i] = s;
    shift2[i] = (b2[i] - mean[i]) * s + beta[i];
}

// ---------------------------------------------------------------- weight conversion (f32 -> f16, MFMA-tile-linear)
// flat pos = (((nt*KS + ks)*4 + kg)*128 + c)*8 + j ; element W[k=ks*32+kg*8+j][n=nt*128+c]
__global__ __launch_bounds__(256) void conv_w_kernel(
    const float* __restrict__ W1, const float* __restrict__ W2,
    ushort* __restrict__ w1h, ushort* __restrict__ w2h)
{
    int i = blockIdx.x * blockDim.x + threadIdx.x;
    const int PER = P1 + P2;
    if (i >= NLAYERS * PER) return;
    int l = i / PER;
    int r = i - l * PER;
    float v;
    ushort* ph;
    if (r < P1) {
        int pos = r;
        int j = pos & 7, c = (pos >> 3) & 127, kg = (pos >> 10) & 3;
        int rest = pos >> 12;
        int ks = rest % KS1, nt = rest / KS1;
        int k = ks * 32 + kg * 8 + j, n = nt * 128 + c;
        v = (k < D && n < HD) ? W1[(size_t)l * D * HD + (size_t)k * HD + n] : 0.f;
        ph = w1h + (size_t)l * P1 + pos;
    } else {
        int pos = r - P1;
        int j = pos & 7, c = (pos >> 3) & 127, kg = (pos >> 10) & 3;
        int rest = pos >> 12;
        int ks = rest % KS2, nt = rest / KS2;
        int k = ks * 32 + kg * 8 + j, n = nt * 128 + c;
        v = (k < HD && n < D) ? W2[(size_t)l * HD * D + (size_t)k * D + n] : 0.f;
        ph = w2h + (size_t)l * P2 + pos;
    }
    *ph = f2h(v);
}

// ---------------------------------------------------------------- fused layer kernel: aggregate + MLP
// EXACT round-10 structure (known-good 312us/1.68ms) + s_setprio only.
// block = 64 node rows, 512 threads (8 waves). LDS 80KB (2 blocks/CU).
template<bool RELU2>
__global__ __launch_bounds__(512, 4) void fused_mlp_kernel(
    const uint* __restrict__ Hin,      // h_in [N][D2] f16x2
    const uint* __restrict__ etab_l,   // [18][D2]
    const int* __restrict__ esrc, const unsigned char* __restrict__ ecomb,
    const int* __restrict__ offsets,
    const uint4* __restrict__ B1,      // W1 tiled, layer base
    const uint4* __restrict__ B2,      // W2 tiled, layer base
    const float* __restrict__ bias1,   // [600]
    const float* __restrict__ scale2,  // [300]
    const float* __restrict__ shift2,  // [300]
    uint* __restrict__ Hout,           // h_out [N][D2] f16x2
    int M)
{
    __shared__ ushort lds[KS2 * 4 * 64 * 8];    // 80 KB, time-multiplexed

    int t = threadIdx.x;
    int lane = t & 63;
    int wid = t >> 6;                 // 0..7
    int lanelo = lane & 15;
    int kg = lane >> 4;
    int m0 = blockIdx.x * 64;

    // ---- Phase 0: gather-aggregate, quarter-wave per row (round-10 exact body) ----
    // lane q = lane>>4 owns row wid*8 + pass*4 + q; ql = lane&15 covers d2 = ql + j*16,
    // j<10 -> exactly [0,160): data (<150) + zero K-pad (150..159).
    {
        uint* ldsAu = (uint*)lds;
        int q = lane >> 4;
        int ql = lane & 15;
#pragma unroll
        for (int pass = 0; pass < 2; ++pass) {
            int rowl = wid * 8 + pass * 4 + q;
            int v = m0 + rowl;
            float ax[10], ay[10];
#pragma unroll
            for (int j = 0; j < 10; ++j) { ax[j] = 0.f; ay[j] = 0.f; }
            if (v < M) {
                int p0 = offsets[v], p1 = offsets[v + 1];
                for (int p = p0; p < p1; ++p) {
                    int s = esrc[p];
                    int c = ecomb[p];
                    const uint* hr = Hin + (size_t)s * D2;
                    const uint* er = etab_l + c * D2;
#pragma unroll
                    for (int j = 0; j < 10; ++j) {
                        int d2 = ql + j * 16;
                        if (d2 < D2) {
                            uint hv = hr[d2];
                            uint ev = er[d2];
                            ax[j] += h2f((ushort)(hv & 0xffffu)) + h2f((ushort)(ev & 0xffffu));
                            ay[j] += h2f((ushort)(hv >> 16))     + h2f((ushort)(ev >> 16));
                        }
                    }
                }
            }
            // swizzled store: chunk = (d2>>2)*64 + (rowl ^ ((d2>>2)&7)); zeros for pad/overrun rows
#pragma unroll
            for (int j = 0; j < 10; ++j) {
                int d2 = ql + j * 16;
                int qc = d2 >> 2;
                ldsAu[(qc * 64 + (rowl ^ (qc & 7))) * 4 + (d2 & 3)] = pack2h(ax[j], ay[j]);
            }
        }
    }
    __syncthreads();

    // ---- Phase 1: GEMM1 (64x640), 1-deep B prefetch, wave wid covers 80 cols ----
    {
        f32x4 acc[4][5];
#pragma unroll
        for (int mi = 0; mi < 4; ++mi)
#pragma unroll
            for (int ni = 0; ni < 5; ++ni) {
                f32x4 z = {0.f, 0.f, 0.f, 0.f};
                acc[mi][ni] = z;
            }

        int addrb[5];
#pragma unroll
        for (int ni = 0; ni < 5; ++ni) {
            int col = wid * 80 + ni * 16 + lanelo;
            int nt = col >> 7, c = col & 127;
            addrb[ni] = nt * (KS1 * 512) + kg * 128 + c;
        }

        uint4 bn[5];
#pragma unroll
        for (int ni = 0; ni < 5; ++ni) bn[ni] = B1[addrb[ni]];

        const f16x8* ap = (const f16x8*)lds;
#pragma unroll
        for (int ks = 0; ks < KS1; ++ks) {
            uint4 bc[5];
#pragma unroll
            for (int ni = 0; ni < 5; ++ni) bc[ni] = bn[ni];
            if (ks + 1 < KS1) {
#pragma unroll
                for (int ni = 0; ni < 5; ++ni) bn[ni] = B1[addrb[ni] + (ks + 1) * 512];
            }
            int q1 = ks * 4 + kg;
            int ab = q1 * 64 + (lanelo ^ (q1 & 7));
            f16x8 a0 = ap[ab];
            f16x8 a1 = ap[ab + 16];
            f16x8 a2 = ap[ab + 32];
            f16x8 a3 = ap[ab + 48];
            __builtin_amdgcn_s_setprio(1);
#pragma unroll
            for (int ni = 0; ni < 5; ++ni) {
                f16x8 b = *(const f16x8*)&bc[ni];
                acc[0][ni] = __builtin_amdgcn_mfma_f32_16x16x32_f16(a0, b, acc[0][ni], 0, 0, 0);
                acc[1][ni] = __builtin_amdgcn_mfma_f32_16x16x32_f16(a1, b, acc[1][ni], 0, 0, 0);
                acc[2][ni] = __builtin_amdgcn_mfma_f32_16x16x32_f16(a2, b, acc[2][ni], 0, 0, 0);
                acc[3][ni] = __builtin_amdgcn_mfma_f32_16x16x32_f16(a3, b, acc[3][ni], 0, 0, 0);
            }
            __builtin_amdgcn_s_setprio(0);
        }

        // all waves done READING ldsA before overwriting with hidden
        __syncthreads();

        // epilogue: +bias, relu; pack adjacent-col pairs via shfl -> b32 LDS writes
        uint* ldsHu = (uint*)lds;
#pragma unroll
        for (int ni = 0; ni < 5; ++ni) {
            int col = wid * 80 + ni * 16 + lanelo;
            float bias = (col < HD) ? bias1[col] : 0.f;
            int ks2 = col >> 5, g2 = (col >> 3) & 3, j2 = col & 7;
            int dbase = (ks2 * 4 + g2) * 256 + (j2 >> 1);
#pragma unroll
            for (int mi = 0; mi < 4; ++mi) {
                int r0 = mi * 16 + kg * 4;
#pragma unroll
                for (int r = 0; r < 4; ++r) {
                    float y = fmaxf(acc[mi][ni][r] + bias, 0.f);
                    float yn = __shfl_xor(y, 1);
                    if ((lanelo & 1) == 0)
                        ldsHu[dbase + (r0 + r) * 4] = pack2h(y, yn);
                }
            }
        }
    }
    __syncthreads();

    // ---- Phase 2: GEMM2 (64x384), 2-deep B prefetch, wave wid covers 48 cols ----
    {
        f32x4 acc[4][3];
#pragma unroll
        for (int mi = 0; mi < 4; ++mi)
#pragma unroll
            for (int ni = 0; ni < 3; ++ni) {
                f32x4 z = {0.f, 0.f, 0.f, 0.f};
                acc[mi][ni] = z;
            }

        int addrb[3];
#pragma unroll
        for (int ni = 0; ni < 3; ++ni) {
            int col = wid * 48 + ni * 16 + lanelo;
            int nt = col >> 7, c = col & 127;
            addrb[ni] = nt * (KS2 * 512) + kg * 128 + c;
        }

        uint4 bn0[3], bn1[3];
#pragma unroll
        for (int ni = 0; ni < 3; ++ni) bn0[ni] = B2[addrb[ni]];
#pragma unroll
        for (int ni = 0; ni < 3; ++ni) bn1[ni] = B2[addrb[ni] + 512];

        const f16x8* hp = (const f16x8*)lds;
#pragma unroll
        for (int ks = 0; ks < KS2; ++ks) {
            uint4 bc[3];
#pragma unroll
            for (int ni = 0; ni < 3; ++ni) bc[ni] = bn0[ni];
#pragma unroll
            for (int ni = 0; ni < 3; ++ni) bn0[ni] = bn1[ni];
            {
                int nk = (ks + 2 < KS2) ? ks + 2 : KS2 - 1;   // clamped, branchless
#pragma unroll
                for (int ni = 0; ni < 3; ++ni) bn1[ni] = B2[addrb[ni] + nk * 512];
            }
            int ab = (ks * 4 + kg) * 64 + lanelo;
            f16x8 a0 = hp[ab];
            f16x8 a1 = hp[ab + 16];
            f16x8 a2 = hp[ab + 32];
            f16x8 a3 = hp[ab + 48];
            __builtin_amdgcn_s_setprio(1);
#pragma unroll
            for (int ni = 0; ni < 3; ++ni) {
                f16x8 b = *(const f16x8*)&bc[ni];
                acc[0][ni] = __builtin_amdgcn_mfma_f32_16x16x32_f16(a0, b, acc[0][ni], 0, 0, 0);
                acc[1][ni] = __builtin_amdgcn_mfma_f32_16x16x32_f16(a1, b, acc[1][ni], 0, 0, 0);
                acc[2][ni] = __builtin_amdgcn_mfma_f32_16x16x32_f16(a2, b, acc[2][ni], 0, 0, 0);
                acc[3][ni] = __builtin_amdgcn_mfma_f32_16x16x32_f16(a3, b, acc[3][ni], 0, 0, 0);
            }
            __builtin_amdgcn_s_setprio(0);
        }

        // all waves done READING ldsH before overwriting with output staging
        __syncthreads();

        // epilogue: BN (+relu); pack pairs -> LDS staging [64][154] uints
        uint* stg = (uint*)lds;
#pragma unroll
        for (int ni = 0; ni < 3; ++ni) {
            int col = wid * 48 + ni * 16 + lanelo;
            float sc = 1.f, sh = 0.f;
            if (col < D) { sc = scale2[col]; sh = shift2[col]; }
#pragma unroll
            for (int mi = 0; mi < 4; ++mi) {
                int r0 = mi * 16 + kg * 4;
#pragma unroll
                for (int r = 0; r < 4; ++r) {
                    float y = acc[mi][ni][r] * sc + sh;
                    if (RELU2) y = fmaxf(y, 0.f);
                    float yn = __shfl_xor(y, 1);
                    if ((lanelo & 1) == 0 && col < D)
                        stg[(r0 + r) * 154 + (col >> 1)] = pack2h(y, yn);
                }
            }
        }
    }
    __syncthreads();

    // ---- coalesced cooperative write: 64 rows x 150 uints ----
    {
        const uint* stg = (const uint*)lds;
#pragma unroll
        for (int i = 0; i < 19; ++i) {
            int g = t + i * 512;
            if (g < 64 * 150) {
                int row = g / 150, c = g - row * 150;
                if (m0 + row < M)
                    Hout[(size_t)(m0 + row) * D2 + c] = stg[row * 154 + c];
            }
        }
    }
}

// ---------------------------------------------------------------- avg pool
__global__ __launch_bounds__(320) void pool_kernel(
    const ushort* __restrict__ h, const int* __restrict__ gid,
    float* __restrict__ gavg, int N)
{
    int g = blockIdx.x;
    int lo = 0, hi = N;
    while (lo < hi) { int mid = (lo + hi) >> 1; if (gid[mid] < g) lo = mid + 1; else hi = mid; }
    int start = lo;
    lo = start; hi = N;
    while (lo < hi) { int mid = (lo + hi) >> 1; if (gid[mid] <= g) lo = mid + 1; else hi = mid; }
    int end = lo;
    int d = threadIdx.x;
    if (d >= D) return;
    float s = 0.f;
    for (int i = start; i < end; ++i) s += h2f(h[(size_t)i * D + d]);
    float cnt = (float)(end - start);
    gavg[(size_t)g * D + d] = s / fmaxf(cnt, 1.f);
}

// ---------------------------------------------------------------- head
__global__ __launch_bounds__(256) void head_kernel(
    const float* __restrict__ gavg, const float* __restrict__ Wd,
    const float* __restrict__ bd, float* __restrict__ out)
{
    int g = blockIdx.x;
    int j = threadIdx.x;
    float s = bd[j];
    const float* gr = gavg + (size_t)g * D;
    for (int d = 0; d < D; ++d) s = fmaf(gr[d], Wd[(size_t)d * 256 + j], s);
    out[(size_t)g * 256 + j] = s;
}

// ================================================================ launch
extern "C" void kernel_launch(void* const* d_in, const int* in_sizes, int n_in,
                              void* d_out, int out_size, void* d_ws, size_t ws_size,
                              hipStream_t stream)
{
    const int*   atomic_number = (const int*)d_in[0];
    const int*   chirality     = (const int*)d_in[1];
    const int*   bond_type     = (const int*)d_in[2];
    const int*   bond_dir      = (const int*)d_in[3];
    const int*   src           = (const int*)d_in[4];
    const int*   dst           = (const int*)d_in[5];
    const int*   graph_ids     = (const int*)d_in[6];
    const float* node_emb0     = (const float*)d_in[8];
    const float* node_emb1     = (const float*)d_in[9];
    const float* edge_emb0     = (const float*)d_in[10];
    const float* edge_emb1     = (const float*)d_in[11];
    const float* W1            = (const float*)d_in[12];
    const float* b1            = (const float*)d_in[13];
    const float* W2            = (const float*)d_in[14];
    const float* b2            = (const float*)d_in[15];
    const float* bn_gamma      = (const float*)d_in[16];
    const float* bn_beta       = (const float*)d_in[17];
    const float* bn_mean       = (const float*)d_in[18];
    const float* bn_var        = (const float*)d_in[19];
    const float* Wd            = (const float*)d_in[20];
    const float* bd            = (const float*)d_in[21];

    int N = in_sizes[0];
    int E = in_sizes[2];
    int G = out_size / 256;
    float* out = (float*)d_out;

    // ---- ws layout (ping-pong h; no agg buffer) ----
    char* ws = (char*)d_ws;
    size_t offs = 0;
    auto take = [&](size_t nbytes) -> char* {
        char* p = ws + offs;
        offs += (nbytes + 255) & ~(size_t)255;
        return p;
    };
    ushort* w1h    = (ushort*)take((size_t)NLAYERS * P1 * 2);
    ushort* w2h    = (ushort*)take((size_t)NLAYERS * P2 * 2);
    uint*   h0     = (uint*)take((size_t)N * D2 * 4);
    uint*   h1     = (uint*)take((size_t)N * D2 * 4);
    int*    deg    = (int*)take((size_t)N * 4);
    int*    offsets= (int*)take((size_t)(N + 1) * 4);
    int*    cursor = (int*)take((size_t)N * 4);
    int*    csr    = (int*)take((size_t)E * 4);
    int*    esrc   = (int*)take((size_t)E * 4);
    unsigned char* ecomb = (unsigned char*)take((size_t)E);
    uint*   etab   = (uint*)take((size_t)NLAYERS * 18 * D2 * 4);
    int*    part   = (int*)take((size_t)256 * 4);
    float*  gavg   = (float*)take((size_t)G * D * 4);
    float*  scale2 = (float*)take((size_t)NLAYERS * D * 4);
    float*  shift2 = (float*)take((size_t)NLAYERS * D * 4);

    // ---- tiny prep ----
    prep_bn_kernel<<<(NLAYERS * D + 255) / 256, 256, 0, stream>>>(
        b2, bn_gamma, bn_beta, bn_mean, bn_var, scale2, shift2, NLAYERS * D);
    {
        int T = NLAYERS * (P1 + P2);
        conv_w_kernel<<<(T + 255) / 256, 256, 0, stream>>>(W1, W2, w1h, w2h);
    }
    etab_kernel<<<(NLAYERS * 18 * D2 + 255) / 256, 256, 0, stream>>>(
        edge_emb0, edge_emb1, etab);
    embed_kernel<<<(N + 3) / 4, 256, 0, stream>>>(
        atomic_number, chirality, node_emb0, node_emb1, h0, N);

    // ---- CSR build (once; layer-invariant) ----
    int NB = (N + SCAN_BLK - 1) / SCAN_BLK;
    zero_kernel<<<(int)(((size_t)N + 1023) / 1024), 256, 0, stream>>>((uint4*)deg, (long)N / 4);
    count_kernel<<<(E + 255) / 256, 256, 0, stream>>>(dst, deg, E);
    scan_part_kernel<<<NB, 256, 0, stream>>>(deg, part, N);
    scan_top_kernel<<<1, 256, 0, stream>>>(part, NB);
    scan_write_kernel<<<NB, 256, 0, stream>>>(deg, part, offsets, cursor, N, E);
    scatter_kernel<<<(E + 255) / 256, 256, 0, stream>>>(dst, cursor, csr, E);
    eprep_kernel<<<(E + 255) / 256, 256, 0, stream>>>(csr, src, bond_type, bond_dir, esrc, ecomb, E);

    int mlp_grid = (N + 63) / 64;
    for (int l = 0; l < NLAYERS; ++l) {
        const uint* hin = (l & 1) ? h1 : h0;
        uint* hout      = (l & 1) ? h0 : h1;
        if (l < NLAYERS - 1)
            fused_mlp_kernel<true><<<mlp_grid, 512, 0, stream>>>(
                hin, etab + (size_t)l * 18 * D2, esrc, ecomb, offsets,
                (const uint4*)(w1h + (size_t)l * P1),
                (const uint4*)(w2h + (size_t)l * P2),
                b1 + (size_t)l * HD,
                scale2 + (size_t)l * D, shift2 + (size_t)l * D,
                hout, N);
        else
            fused_mlp_kernel<false><<<mlp_grid, 512, 0, stream>>>(
                hin, etab + (size_t)l * 18 * D2, esrc, ecomb, offsets,
                (const uint4*)(w1h + (size_t)l * P1),
                (const uint4*)(w2h + (size_t)l * P2),
                b1 + (size_t)l * HD,
                scale2 + (size_t)l * D, shift2 + (size_t)l * D,
                hout, N);
    }

    // final h is h1 (odd number of layers -> last write went to h1)
    pool_kernel<<<G, 320, 0, stream>>>((const ushort*)h1, graph_ids, gavg, N);
    head_kernel<<<G, 256, 0, stream>>>(gavg, Wd, bd, out);
}

// Round 14
// 1674.209 us; speedup vs baseline: 2.1485x; 2.1485x over previous
//
#include <hip/hip_runtime.h>
#include <hip/hip_bf16.h>
#include <hip/hip_fp16.h>

#define D 300
#define D2 150          // f16 pairs per row
#define HD 600
#define NLAYERS 5
#define BN_EPS 1e-5f

// GEMM1: K=300->320 (KS1=10), N=600->640. GEMM2: K=600->640 (KS2=20), N=300->384.
#define KS1 10
#define NT1 5
#define KS2 20
#define NT2 3
#define P1 (NT1*KS1*4096)   // 204800 f16 per layer (w1 tiled)
#define P2 (NT2*KS2*4096)   // 245760 f16 per layer (w2 tiled)

#define SCAN_BLK 1024

typedef _Float16 f16x8 __attribute__((ext_vector_type(8)));
typedef __attribute__((ext_vector_type(4))) float f32x4;

// ---------------------------------------------------------------- f16 helpers
__device__ inline ushort f2h(float x) {
    __half h = __float2half(x);
    return *reinterpret_cast<ushort*>(&h);
}
__device__ inline float h2f(ushort u) {
    __half h;
    *reinterpret_cast<ushort*>(&h) = u;
    return __half2float(h);
}
__device__ inline uint pack2h(float lo, float hi) {
    return (uint)f2h(lo) | ((uint)f2h(hi) << 16);
}

// ---------------------------------------------------------------- zero fill
__global__ __launch_bounds__(256) void zero_kernel(uint4* __restrict__ p, long n4)
{
    long i = (long)blockIdx.x * blockDim.x + threadIdx.x;
    long stride = (long)gridDim.x * blockDim.x;
    uint4 z = make_uint4(0u, 0u, 0u, 0u);
    for (; i < n4; i += stride) p[i] = z;
}

// ---------------------------------------------------------------- embed (h f16)
__global__ __launch_bounds__(256) void embed_kernel(
    const int* __restrict__ an, const int* __restrict__ ch,
    const float* __restrict__ e0, const float* __restrict__ e1,
    uint* __restrict__ h_u, int N)
{
    int node = blockIdx.x * 4 + (threadIdx.x >> 6);
    if (node >= N) return;
    int lane = threadIdx.x & 63;
    const float* r0 = e0 + (size_t)an[node] * D;
    const float* r1 = e1 + (size_t)ch[node] * D;
    uint* hr = h_u + (size_t)node * D2;
    for (int d2 = lane; d2 < D2; d2 += 64) {
        float2 a = *(const float2*)(r0 + d2 * 2);
        float2 b = *(const float2*)(r1 + d2 * 2);
        hr[d2] = pack2h(a.x + b.x, a.y + b.y);
    }
}

// ---------------------------------------------------------------- CSR build (once)
__global__ __launch_bounds__(256) void count_kernel(
    const int* __restrict__ dst, int* __restrict__ deg, int E)
{
    int e = blockIdx.x * 256 + threadIdx.x;
    if (e < E) atomicAdd(&deg[dst[e]], 1);
}

__global__ __launch_bounds__(256) void scan_part_kernel(
    const int* __restrict__ deg, int* __restrict__ part, int N)
{
    __shared__ int sm[256];
    int b = blockIdx.x, t = threadIdx.x;
    int base = b * SCAN_BLK + t * 4;
    int s = 0;
#pragma unroll
    for (int j = 0; j < 4; ++j) { int i = base + j; if (i < N) s += deg[i]; }
    sm[t] = s;
    __syncthreads();
    for (int off = 128; off > 0; off >>= 1) {
        if (t < off) sm[t] += sm[t + off];
        __syncthreads();
    }
    if (t == 0) part[b] = sm[0];
}

__global__ __launch_bounds__(256) void scan_top_kernel(int* __restrict__ part, int NB)
{
    __shared__ int sm[256];
    int t = threadIdx.x;
    int own = (t < NB) ? part[t] : 0;
    sm[t] = own;
    __syncthreads();
    for (int off = 1; off < 256; off <<= 1) {
        int u = (t >= off) ? sm[t - off] : 0;
        __syncthreads();
        sm[t] += u;
        __syncthreads();
    }
    if (t < NB) part[t] = sm[t] - own;   // exclusive
}

__global__ __launch_bounds__(256) void scan_write_kernel(
    const int* __restrict__ deg, const int* __restrict__ part,
    int* __restrict__ offsets, int* __restrict__ cursor, int N, int E)
{
    __shared__ int sm[256];
    int b = blockIdx.x, t = threadIdx.x;
    int base = b * SCAN_BLK + t * 4;
    int v[4], s = 0;
#pragma unroll
    for (int j = 0; j < 4; ++j) { int i = base + j; v[j] = (i < N) ? deg[i] : 0; s += v[j]; }
    int own = s;
    sm[t] = s;
    __syncthreads();
    for (int off = 1; off < 256; off <<= 1) {
        int u = (t >= off) ? sm[t - off] : 0;
        __syncthreads();
        sm[t] += u;
        __syncthreads();
    }
    int ex = sm[t] - own + part[b];
#pragma unroll
    for (int j = 0; j < 4; ++j) {
        int i = base + j;
        if (i < N) { offsets[i] = ex; cursor[i] = ex; ex += v[j]; }
    }
    if (b == 0 && t == 0) offsets[N] = E;
}

__global__ __launch_bounds__(256) void scatter_kernel(
    const int* __restrict__ dst, int* __restrict__ cursor,
    int* __restrict__ csr, int E)
{
    int e = blockIdx.x * 256 + threadIdx.x;
    if (e < E) {
        int pos = atomicAdd(&cursor[dst[e]], 1);
        csr[pos] = e;
    }
}

// ---------------------------------------------------------------- edge prep (once): CSR-ordered src + combo id
__global__ __launch_bounds__(256) void eprep_kernel(
    const int* __restrict__ csr, const int* __restrict__ src,
    const int* __restrict__ bt, const int* __restrict__ bd,
    int* __restrict__ esrc, unsigned char* __restrict__ ecomb, int E)
{
    int p = blockIdx.x * 256 + threadIdx.x;
    if (p < E) {
        int e = csr[p];
        esrc[p] = src[e];
        ecomb[p] = (unsigned char)(bt[e] * 3 + bd[e]);
    }
}

// ---------------------------------------------------------------- edge-emb combo table: etab[l][c=bt*3+bd][D2] f16x2
__global__ __launch_bounds__(256) void etab_kernel(
    const float* __restrict__ ee0, const float* __restrict__ ee1,
    uint* __restrict__ etab)
{
    int i = blockIdx.x * 256 + threadIdx.x;
    const int total = NLAYERS * 18 * D2;
    if (i >= total) return;
    int d2 = i % D2;
    int rest = i / D2;
    int c = rest % 18, l = rest / 18;
    int btv = c / 3, bdv = c % 3;
    const float* r0 = ee0 + ((size_t)l * 6 + btv) * D + d2 * 2;
    const float* r1 = ee1 + ((size_t)l * 3 + bdv) * D + d2 * 2;
    etab[i] = pack2h(r0[0] + r1[0], r0[1] + r1[1]);
}

// ---------------------------------------------------------------- BN fold prep
__global__ void prep_bn_kernel(
    const float* __restrict__ b2, const float* __restrict__ gamma,
    const float* __restrict__ beta, const float* __restrict__ mean,
    const float* __restrict__ var, float* __restrict__ scale2,
    float* __restrict__ shift2, int n)
{
    int i = blockIdx.x * blockDim.x + threadIdx.x;
    if (i >= n) return;
    float s = gamma[i] * rsqrtf(var[i] + BN_EPS);
    scale2[i] = s;
    shift2[i] = (b2[i] - mean[i]) * s + beta[i];
}

// ---------------------------------------------------------------- weight conversion (f32 -> f16, MFMA-tile-linear)
// flat pos = (((nt*KS + ks)*4 + kg)*128 + c)*8 + j ; element W[k=ks*32+kg*8+j][n=nt*128+c]
__global__ __launch_bounds__(256) void conv_w_kernel(
    const float* __restrict__ W1, const float* __restrict__ W2,
    ushort* __restrict__ w1h, ushort* __restrict__ w2h)
{
    int i = blockIdx.x * blockDim.x + threadIdx.x;
    const int PER = P1 + P2;
    if (i >= NLAYERS * PER) return;
    int l = i / PER;
    int r = i - l * PER;
    float v;
    ushort* ph;
    if (r < P1) {
        int pos = r;
        int j = pos & 7, c = (pos >> 3) & 127, kg = (pos >> 10) & 3;
        int rest = pos >> 12;
        int ks = rest % KS1, nt = rest / KS1;
        int k = ks * 32 + kg * 8 + j, n = nt * 128 + c;
        v = (k < D && n < HD) ? W1[(size_t)l * D * HD + (size_t)k * HD + n] : 0.f;
        ph = w1h + (size_t)l * P1 + pos;
    } else {
        int pos = r - P1;
        int j = pos & 7, c = (pos >> 3) & 127, kg = (pos >> 10) & 3;
        int rest = pos >> 12;
        int ks = rest % KS2, nt = rest / KS2;
        int k = ks * 32 + kg * 8 + j, n = nt * 128 + c;
        v = (k < HD && n < D) ? W2[(size_t)l * HD * D + (size_t)k * D + n] : 0.f;
        ph = w2h + (size_t)l * P2 + pos;
    }
    *ph = f2h(v);
}

// ---------------------------------------------------------------- fused layer kernel: aggregate + MLP
// EXACT round-10 known-good version (312us/dispatch, 1.68ms total).
// NOTE: s_setprio inside these unrolled MFMA loops triggers scratch spill
// (rounds 11-13: WRITE 142MB -> 1.6GB, 2x slowdown). Do NOT add it back.
// block = 64 node rows, 512 threads (8 waves). LDS 80KB (2 blocks/CU).
template<bool RELU2>
__global__ __launch_bounds__(512, 4) void fused_mlp_kernel(
    const uint* __restrict__ Hin,      // h_in [N][D2] f16x2
    const uint* __restrict__ etab_l,   // [18][D2]
    const int* __restrict__ esrc, const unsigned char* __restrict__ ecomb,
    const int* __restrict__ offsets,
    const uint4* __restrict__ B1,      // W1 tiled, layer base
    const uint4* __restrict__ B2,      // W2 tiled, layer base
    const float* __restrict__ bias1,   // [600]
    const float* __restrict__ scale2,  // [300]
    const float* __restrict__ shift2,  // [300]
    uint* __restrict__ Hout,           // h_out [N][D2] f16x2
    int M)
{
    __shared__ ushort lds[KS2 * 4 * 64 * 8];    // 80 KB, time-multiplexed

    int t = threadIdx.x;
    int lane = t & 63;
    int wid = t >> 6;                 // 0..7
    int lanelo = lane & 15;
    int kg = lane >> 4;
    int m0 = blockIdx.x * 64;

    // ---- Phase 0: gather-aggregate, quarter-wave per row ----
    // lane q = lane>>4 owns row wid*8 + pass*4 + q; ql = lane&15 covers d2 = ql + j*16,
    // j<10 -> exactly [0,160): data (<150) + zero K-pad (150..159).
    {
        uint* ldsAu = (uint*)lds;
        int q = lane >> 4;
        int ql = lane & 15;
#pragma unroll
        for (int pass = 0; pass < 2; ++pass) {
            int rowl = wid * 8 + pass * 4 + q;
            int v = m0 + rowl;
            float ax[10], ay[10];
#pragma unroll
            for (int j = 0; j < 10; ++j) { ax[j] = 0.f; ay[j] = 0.f; }
            if (v < M) {
                int p0 = offsets[v], p1 = offsets[v + 1];
                for (int p = p0; p < p1; ++p) {
                    int s = esrc[p];
                    int c = ecomb[p];
                    const uint* hr = Hin + (size_t)s * D2;
                    const uint* er = etab_l + c * D2;
#pragma unroll
                    for (int j = 0; j < 10; ++j) {
                        int d2 = ql + j * 16;
                        if (d2 < D2) {
                            uint hv = hr[d2];
                            uint ev = er[d2];
                            ax[j] += h2f((ushort)(hv & 0xffffu)) + h2f((ushort)(ev & 0xffffu));
                            ay[j] += h2f((ushort)(hv >> 16))     + h2f((ushort)(ev >> 16));
                        }
                    }
                }
            }
            // swizzled store: chunk = (d2>>2)*64 + (rowl ^ ((d2>>2)&7)); zeros for pad/overrun rows
#pragma unroll
            for (int j = 0; j < 10; ++j) {
                int d2 = ql + j * 16;
                int qc = d2 >> 2;
                ldsAu[(qc * 64 + (rowl ^ (qc & 7))) * 4 + (d2 & 3)] = pack2h(ax[j], ay[j]);
            }
        }
    }
    __syncthreads();

    // ---- Phase 1: GEMM1 (64x640), 1-deep B prefetch, wave wid covers 80 cols ----
    {
        f32x4 acc[4][5];
#pragma unroll
        for (int mi = 0; mi < 4; ++mi)
#pragma unroll
            for (int ni = 0; ni < 5; ++ni) {
                f32x4 z = {0.f, 0.f, 0.f, 0.f};
                acc[mi][ni] = z;
            }

        int addrb[5];
#pragma unroll
        for (int ni = 0; ni < 5; ++ni) {
            int col = wid * 80 + ni * 16 + lanelo;
            int nt = col >> 7, c = col & 127;
            addrb[ni] = nt * (KS1 * 512) + kg * 128 + c;
        }

        uint4 bn[5];
#pragma unroll
        for (int ni = 0; ni < 5; ++ni) bn[ni] = B1[addrb[ni]];

        const f16x8* ap = (const f16x8*)lds;
#pragma unroll
        for (int ks = 0; ks < KS1; ++ks) {
            uint4 bc[5];
#pragma unroll
            for (int ni = 0; ni < 5; ++ni) bc[ni] = bn[ni];
            if (ks + 1 < KS1) {
#pragma unroll
                for (int ni = 0; ni < 5; ++ni) bn[ni] = B1[addrb[ni] + (ks + 1) * 512];
            }
            int q1 = ks * 4 + kg;
            int ab = q1 * 64 + (lanelo ^ (q1 & 7));
            f16x8 a0 = ap[ab];
            f16x8 a1 = ap[ab + 16];
            f16x8 a2 = ap[ab + 32];
            f16x8 a3 = ap[ab + 48];
#pragma unroll
            for (int ni = 0; ni < 5; ++ni) {
                f16x8 b = *(const f16x8*)&bc[ni];
                acc[0][ni] = __builtin_amdgcn_mfma_f32_16x16x32_f16(a0, b, acc[0][ni], 0, 0, 0);
                acc[1][ni] = __builtin_amdgcn_mfma_f32_16x16x32_f16(a1, b, acc[1][ni], 0, 0, 0);
                acc[2][ni] = __builtin_amdgcn_mfma_f32_16x16x32_f16(a2, b, acc[2][ni], 0, 0, 0);
                acc[3][ni] = __builtin_amdgcn_mfma_f32_16x16x32_f16(a3, b, acc[3][ni], 0, 0, 0);
            }
        }

        // all waves done READING ldsA before overwriting with hidden
        __syncthreads();

        // epilogue: +bias, relu; pack adjacent-col pairs via shfl -> b32 LDS writes
        uint* ldsHu = (uint*)lds;
#pragma unroll
        for (int ni = 0; ni < 5; ++ni) {
            int col = wid * 80 + ni * 16 + lanelo;
            float bias = (col < HD) ? bias1[col] : 0.f;
            int ks2 = col >> 5, g2 = (col >> 3) & 3, j2 = col & 7;
            int dbase = (ks2 * 4 + g2) * 256 + (j2 >> 1);
#pragma unroll
            for (int mi = 0; mi < 4; ++mi) {
                int r0 = mi * 16 + kg * 4;
#pragma unroll
                for (int r = 0; r < 4; ++r) {
                    float y = fmaxf(acc[mi][ni][r] + bias, 0.f);
                    float yn = __shfl_xor(y, 1);
                    if ((lanelo & 1) == 0)
                        ldsHu[dbase + (r0 + r) * 4] = pack2h(y, yn);
                }
            }
        }
    }
    __syncthreads();

    // ---- Phase 2: GEMM2 (64x384), 2-deep B prefetch, wave wid covers 48 cols ----
    {
        f32x4 acc[4][3];
#pragma unroll
        for (int mi = 0; mi < 4; ++mi)
#pragma unroll
            for (int ni = 0; ni < 3; ++ni) {
                f32x4 z = {0.f, 0.f, 0.f, 0.f};
                acc[mi][ni] = z;
            }

        int addrb[3];
#pragma unroll
        for (int ni = 0; ni < 3; ++ni) {
            int col = wid * 48 + ni * 16 + lanelo;
            int nt = col >> 7, c = col & 127;
            addrb[ni] = nt * (KS2 * 512) + kg * 128 + c;
        }

        uint4 bn0[3], bn1[3];
#pragma unroll
        for (int ni = 0; ni < 3; ++ni) bn0[ni] = B2[addrb[ni]];
#pragma unroll
        for (int ni = 0; ni < 3; ++ni) bn1[ni] = B2[addrb[ni] + 512];

        const f16x8* hp = (const f16x8*)lds;
#pragma unroll
        for (int ks = 0; ks < KS2; ++ks) {
            uint4 bc[3];
#pragma unroll
            for (int ni = 0; ni < 3; ++ni) bc[ni] = bn0[ni];
#pragma unroll
            for (int ni = 0; ni < 3; ++ni) bn0[ni] = bn1[ni];
            {
                int nk = (ks + 2 < KS2) ? ks + 2 : KS2 - 1;   // clamped, branchless
#pragma unroll
                for (int ni = 0; ni < 3; ++ni) bn1[ni] = B2[addrb[ni] + nk * 512];
            }
            int ab = (ks * 4 + kg) * 64 + lanelo;
            f16x8 a0 = hp[ab];
            f16x8 a1 = hp[ab + 16];
            f16x8 a2 = hp[ab + 32];
            f16x8 a3 = hp[ab + 48];
#pragma unroll
            for (int ni = 0; ni < 3; ++ni) {
                f16x8 b = *(const f16x8*)&bc[ni];
                acc[0][ni] = __builtin_amdgcn_mfma_f32_16x16x32_f16(a0, b, acc[0][ni], 0, 0, 0);
                acc[1][ni] = __builtin_amdgcn_mfma_f32_16x16x32_f16(a1, b, acc[1][ni], 0, 0, 0);
                acc[2][ni] = __builtin_amdgcn_mfma_f32_16x16x32_f16(a2, b, acc[2][ni], 0, 0, 0);
                acc[3][ni] = __builtin_amdgcn_mfma_f32_16x16x32_f16(a3, b, acc[3][ni], 0, 0, 0);
            }
        }

        // all waves done READING ldsH before overwriting with output staging
        __syncthreads();

        // epilogue: BN (+relu); pack pairs -> LDS staging [64][154] uints
        uint* stg = (uint*)lds;
#pragma unroll
        for (int ni = 0; ni < 3; ++ni) {
            int col = wid * 48 + ni * 16 + lanelo;
            float sc = 1.f, sh = 0.f;
            if (col < D) { sc = scale2[col]; sh = shift2[col]; }
#pragma unroll
            for (int mi = 0; mi < 4; ++mi) {
                int r0 = mi * 16 + kg * 4;
#pragma unroll
                for (int r = 0; r < 4; ++r) {
                    float y = acc[mi][ni][r] * sc + sh;
                    if (RELU2) y = fmaxf(y, 0.f);
                    float yn = __shfl_xor(y, 1);
                    if ((lanelo & 1) == 0 && col < D)
                        stg[(r0 + r) * 154 + (col >> 1)] = pack2h(y, yn);
                }
            }
        }
    }
    __syncthreads();

    // ---- coalesced cooperative write: 64 rows x 150 uints ----
    {
        const uint* stg = (const uint*)lds;
#pragma unroll
        for (int i = 0; i < 19; ++i) {
            int g = t + i * 512;
            if (g < 64 * 150) {
                int row = g / 150, c = g - row * 150;
                if (m0 + row < M)
                    Hout[(size_t)(m0 + row) * D2 + c] = stg[row * 154 + c];
            }
        }
    }
}

// ---------------------------------------------------------------- avg pool
__global__ __launch_bounds__(320) void pool_kernel(
    const ushort* __restrict__ h, const int* __restrict__ gid,
    float* __restrict__ gavg, int N)
{
    int g = blockIdx.x;
    int lo = 0, hi = N;
    while (lo < hi) { int mid = (lo + hi) >> 1; if (gid[mid] < g) lo = mid + 1; else hi = mid; }
    int start = lo;
    lo = start; hi = N;
    while (lo < hi) { int mid = (lo + hi) >> 1; if (gid[mid] <= g) lo = mid + 1; else hi = mid; }
    int end = lo;
    int d = threadIdx.x;
    if (d >= D) return;
    float s = 0.f;
    for (int i = start; i < end; ++i) s += h2f(h[(size_t)i * D + d]);
    float cnt = (float)(end - start);
    gavg[(size_t)g * D + d] = s / fmaxf(cnt, 1.f);
}

// ---------------------------------------------------------------- head
__global__ __launch_bounds__(256) void head_kernel(
    const float* __restrict__ gavg, const float* __restrict__ Wd,
    const float* __restrict__ bd, float* __restrict__ out)
{
    int g = blockIdx.x;
    int j = threadIdx.x;
    float s = bd[j];
    const float* gr = gavg + (size_t)g * D;
    for (int d = 0; d < D; ++d) s = fmaf(gr[d], Wd[(size_t)d * 256 + j], s);
    out[(size_t)g * 256 + j] = s;
}

// ================================================================ launch
extern "C" void kernel_launch(void* const* d_in, const int* in_sizes, int n_in,
                              void* d_out, int out_size, void* d_ws, size_t ws_size,
                              hipStream_t stream)
{
    const int*   atomic_number = (const int*)d_in[0];
    const int*   chirality     = (const int*)d_in[1];
    const int*   bond_type     = (const int*)d_in[2];
    const int*   bond_dir      = (const int*)d_in[3];
    const int*   src           = (const int*)d_in[4];
    const int*   dst           = (const int*)d_in[5];
    const int*   graph_ids     = (const int*)d_in[6];
    const float* node_emb0     = (const float*)d_in[8];
    const float* node_emb1     = (const float*)d_in[9];
    const float* edge_emb0     = (const float*)d_in[10];
    const float* edge_emb1     = (const float*)d_in[11];
    const float* W1            = (const float*)d_in[12];
    const float* b1            = (const float*)d_in[13];
    const float* W2            = (const float*)d_in[14];
    const float* b2            = (const float*)d_in[15];
    const float* bn_gamma      = (const float*)d_in[16];
    const float* bn_beta       = (const float*)d_in[17];
    const float* bn_mean       = (const float*)d_in[18];
    const float* bn_var        = (const float*)d_in[19];
    const float* Wd            = (const float*)d_in[20];
    const float* bd            = (const float*)d_in[21];

    int N = in_sizes[0];
    int E = in_sizes[2];
    int G = out_size / 256;
    float* out = (float*)d_out;

    // ---- ws layout (ping-pong h; no agg buffer) ----
    char* ws = (char*)d_ws;
    size_t offs = 0;
    auto take = [&](size_t nbytes) -> char* {
        char* p = ws + offs;
        offs += (nbytes + 255) & ~(size_t)255;
        return p;
    };
    ushort* w1h    = (ushort*)take((size_t)NLAYERS * P1 * 2);
    ushort* w2h    = (ushort*)take((size_t)NLAYERS * P2 * 2);
    uint*   h0     = (uint*)take((size_t)N * D2 * 4);
    uint*   h1     = (uint*)take((size_t)N * D2 * 4);
    int*    deg    = (int*)take((size_t)N * 4);
    int*    offsets= (int*)take((size_t)(N + 1) * 4);
    int*    cursor = (int*)take((size_t)N * 4);
    int*    csr    = (int*)take((size_t)E * 4);
    int*    esrc   = (int*)take((size_t)E * 4);
    unsigned char* ecomb = (unsigned char*)take((size_t)E);
    uint*   etab   = (uint*)take((size_t)NLAYERS * 18 * D2 * 4);
    int*    part   = (int*)take((size_t)256 * 4);
    float*  gavg   = (float*)take((size_t)G * D * 4);
    float*  scale2 = (float*)take((size_t)NLAYERS * D * 4);
    float*  shift2 = (float*)take((size_t)NLAYERS * D * 4);

    // ---- tiny prep ----
    prep_bn_kernel<<<(NLAYERS * D + 255) / 256, 256, 0, stream>>>(
        b2, bn_gamma, bn_beta, bn_mean, bn_var, scale2, shift2, NLAYERS * D);
    {
        int T = NLAYERS * (P1 + P2);
        conv_w_kernel<<<(T + 255) / 256, 256, 0, stream>>>(W1, W2, w1h, w2h);
    }
    etab_kernel<<<(NLAYERS * 18 * D2 + 255) / 256, 256, 0, stream>>>(
        edge_emb0, edge_emb1, etab);
    embed_kernel<<<(N + 3) / 4, 256, 0, stream>>>(
        atomic_number, chirality, node_emb0, node_emb1, h0, N);

    // ---- CSR build (once; layer-invariant) ----
    int NB = (N + SCAN_BLK - 1) / SCAN_BLK;
    zero_kernel<<<(int)(((size_t)N + 1023) / 1024), 256, 0, stream>>>((uint4*)deg, (long)N / 4);
    count_kernel<<<(E + 255) / 256, 256, 0, stream>>>(dst, deg, E);
    scan_part_kernel<<<NB, 256, 0, stream>>>(deg, part, N);
    scan_top_kernel<<<1, 256, 0, stream>>>(part, NB);
    scan_write_kernel<<<NB, 256, 0, stream>>>(deg, part, offsets, cursor, N, E);
    scatter_kernel<<<(E + 255) / 256, 256, 0, stream>>>(dst, cursor, csr, E);
    eprep_kernel<<<(E + 255) / 256, 256, 0, stream>>>(csr, src, bond_type, bond_dir, esrc, ecomb, E);

    int mlp_grid = (N + 63) / 64;
    for (int l = 0; l < NLAYERS; ++l) {
        const uint* hin = (l & 1) ? h1 : h0;
        uint* hout      = (l & 1) ? h0 : h1;
        if (l < NLAYERS - 1)
            fused_mlp_kernel<true><<<mlp_grid, 512, 0, stream>>>(
                hin, etab + (size_t)l * 18 * D2, esrc, ecomb, offsets,
                (const uint4*)(w1h + (size_t)l * P1),
                (const uint4*)(w2h + (size_t)l * P2),
                b1 + (size_t)l * HD,
                scale2 + (size_t)l * D, shift2 + (size_t)l * D,
                hout, N);
        else
            fused_mlp_kernel<false><<<mlp_grid, 512, 0, stream>>>(
                hin, etab + (size_t)l * 18 * D2, esrc, ecomb, offsets,
                (const uint4*)(w1h + (size_t)l * P1),
                (const uint4*)(w2h + (size_t)l * P2),
                b1 + (size_t)l * HD,
                scale2 + (size_t)l * D, shift2 + (size_t)l * D,
                hout, N);
    }

    // final h is h1 (odd number of layers -> last write went to h1)
    pool_kernel<<<G, 320, 0, stream>>>((const ushort*)h1, graph_ids, gavg, N);
    head_kernel<<<G, 256, 0, stream>>>(gavg, Wd, bd, out);
}